// Round 5
// baseline (141.548 us; speedup 1.0000x reference)
//
#include <hip/hip_runtime.h>
#include <hip/hip_bf16.h>
#include <stdint.h>

#define QMAX 127.0f

typedef __attribute__((ext_vector_type(4))) int   i32x4;
typedef __attribute__((ext_vector_type(2))) int   i32x2;

__device__ inline int quant_i(float x, float inv) {
    float q = rintf(x * inv);                 // inv = 127/absmax (one div per row)
    q = fminf(fmaxf(q, -QMAX), QMAX);
    return (int)q;                            // exact: q integral, |q|<=127
}

// ---- kernel 1: quantize rhs along axis 0 (per column f), store B^T int8 [F][K] ----
__global__ void quant_rhs_kernel(const float* __restrict__ rhs,
                                 int8_t* __restrict__ Bt,
                                 float* __restrict__ rscale) {
    const int f = blockIdx.x;      // column 0..511
    const int t = threadIdx.x;     // 0..63
    float v[8];
    float amax = 0.f;
#pragma unroll
    for (int i = 0; i < 8; ++i) {
        v[i] = rhs[(size_t)(t + 64 * i) * 512 + f];
        amax = fmaxf(amax, fabsf(v[i]));
    }
#pragma unroll
    for (int m = 1; m <= 32; m <<= 1)
        amax = fmaxf(amax, __shfl_xor(amax, m, 64));
    const float inv = amax > 0.f ? QMAX / amax : 0.f;
    if (t == 0) rscale[f] = amax > 0.f ? amax * (1.0f / QMAX) : 1.0f;
#pragma unroll
    for (int i = 0; i < 8; ++i)
        Bt[(size_t)f * 512 + t + 64 * i] = (int8_t)quant_i(v[i], inv);
}

// ---- kernel 2: fused quant(lhs) + int8 GEMM ----
// Block = 256 threads (4 waves), 16 rows x full N=512.
// Phase 1: each wave quantizes 4 rows -> int8 into XOR-swizzled LDS (8KB).
// Phase 2: wave w computes 16 rows x cols [w*128, w*128+128):
//   8 K-steps of mfma_i32_16x16x64_i8; A from LDS, B from L2-resident Bt int8.
// acc = 8 x i32x4 = 32 regs -> ~20 waves/CU occupancy, real prefetch slack.
__global__ __launch_bounds__(256, 4) void fused_kernel(const float* __restrict__ lhs,
                                                       const int8_t* __restrict__ Bt,
                                                       const float* __restrict__ rscale,
                                                       float* __restrict__ out) {
    __shared__ int8_t A[16 * 512];   // [16 rows][512 k] int8, XOR-swizzled
    __shared__ float lsc[16];

    const int tid  = threadIdx.x;
    const int lane = tid & 63;
    const int wave = tid >> 6;          // 0..3
    const int m0   = blockIdx.x << 4;   // 16 rows per block

    // ---- phase 1: quantize rows m0..m0+15; wave w owns rows w*4..w*4+3 ----
    {
        const float* bp = lhs + (size_t)(m0 + wave * 4) * 512 + lane * 8;
        float4 v0[4], v1[4];
#pragma unroll
        for (int r = 0; r < 4; ++r) {                 // batch all 8 loads (32 regs)
            v0[r] = *(const float4*)(bp + (size_t)r * 512);
            v1[r] = *(const float4*)(bp + (size_t)r * 512 + 4);
        }
#pragma unroll
        for (int r = 0; r < 4; ++r) {
            const int row = wave * 4 + r;
            const float4 a = v0[r], b = v1[r];
            float amax = fmaxf(fmaxf(fmaxf(fabsf(a.x), fabsf(a.y)), fmaxf(fabsf(a.z), fabsf(a.w))),
                               fmaxf(fmaxf(fabsf(b.x), fabsf(b.y)), fmaxf(fabsf(b.z), fabsf(b.w))));
#pragma unroll
            for (int m = 1; m <= 32; m <<= 1)
                amax = fmaxf(amax, __shfl_xor(amax, m, 64));
            const float inv = amax > 0.f ? QMAX / amax : 0.f;
            if (lane == 0) lsc[row] = amax > 0.f ? amax * (1.0f / QMAX) : 1.0f;
            uint32_t p0 = (uint32_t)(quant_i(a.x, inv) & 255)
                        | ((uint32_t)(quant_i(a.y, inv) & 255) << 8)
                        | ((uint32_t)(quant_i(a.z, inv) & 255) << 16)
                        | ((uint32_t)(quant_i(a.w, inv) & 255) << 24);
            uint32_t p1 = (uint32_t)(quant_i(b.x, inv) & 255)
                        | ((uint32_t)(quant_i(b.y, inv) & 255) << 8)
                        | ((uint32_t)(quant_i(b.z, inv) & 255) << 16)
                        | ((uint32_t)(quant_i(b.w, inv) & 255) << 24);
            i32x2 p; p.x = (int)p0; p.y = (int)p1;
            const int off = (row * 512 + lane * 8) ^ ((row & 7) << 4);  // 8B-safe XOR
            *(i32x2*)((char*)A + off) = p;
        }
    }
    __syncthreads();

    // ---- phase 2: wave w -> cols [w*128, w*128+128), 8 K-steps of K=64 ----
    const int lane15  = lane & 15;
    const int laneHi  = lane >> 4;
    const int colBase = wave * 128;
    const int8_t* bp0 = Bt + (size_t)(colBase + lane15) * 512 + laneHi * 16;
    const int aBase   = lane15 * 512 + laneHi * 16;   // swizzle applied per-ks
    const int sw      = (lane15 & 7) << 4;

    i32x4 acc[8];
#pragma unroll
    for (int n = 0; n < 8; ++n) acc[n] = (i32x4){0, 0, 0, 0};

#pragma unroll
    for (int ks = 0; ks < 8; ++ks) {                  // k = ks*64
        i32x4 bfr[8];
#pragma unroll
        for (int ni = 0; ni < 8; ++ni)                // 8 x 16B from L2
            bfr[ni] = *(const i32x4*)(bp0 + (size_t)ni * 16 * 512 + ks * 64);
        const i32x4 af = *(const i32x4*)((const char*)A + ((aBase + ks * 64) ^ sw));
#pragma unroll
        for (int ni = 0; ni < 8; ++ni)
            acc[ni] = __builtin_amdgcn_mfma_i32_16x16x64_i8(af, bfr[ni], acc[ni], 0, 0, 0);
    }

    // ---- epilogue: C/D layout col=lane&15, row=(lane>>4)*4+reg ----
    float rs[8];
#pragma unroll
    for (int ni = 0; ni < 8; ++ni)
        rs[ni] = rscale[colBase + ni * 16 + lane15];
    const int rg = laneHi * 4;
#pragma unroll
    for (int r = 0; r < 4; ++r) {
        const int lrow = rg + r;
        const float ls = lsc[lrow];
        float* op = out + (size_t)(m0 + lrow) * 512;
#pragma unroll
        for (int ni = 0; ni < 8; ++ni)
            op[colBase + ni * 16 + lane15] = (float)acc[ni][r] * ls * rs[ni];
    }
}

extern "C" void kernel_launch(void* const* d_in, const int* in_sizes, int n_in,
                              void* d_out, int out_size, void* d_ws, size_t ws_size,
                              hipStream_t stream) {
    const float* lhs = (const float*)d_in[0];   // [4,16384,512] f32
    const float* rhs = (const float*)d_in[1];   // [512,512] f32
    float* out = (float*)d_out;                 // [4,16384,512] f32

    char* ws = (char*)d_ws;
    int8_t* Bt    = (int8_t*)ws;                // 256KB, int8 [col][k]
    float* rscale = (float*)(ws + 262144);

    const int rows = in_sizes[0] / 512;         // 65536

    quant_rhs_kernel<<<512, 64, 0, stream>>>(rhs, Bt, rscale);
    fused_kernel<<<rows / 16, 256, 0, stream>>>(lhs, Bt, rscale, out);
}

// Round 6
// 73.210 us; speedup vs baseline: 1.9334x; 1.9334x over previous
//
#include <hip/hip_runtime.h>
#include <hip/hip_bf16.h>
#include <stdint.h>

#define QMAX 127.0f

typedef __attribute__((ext_vector_type(4))) int i32x4;
typedef __attribute__((ext_vector_type(2))) int i32x2;

typedef __attribute__((address_space(1))) const void GVoid;
typedef __attribute__((address_space(3))) void LVoid;

__device__ inline int quant_i(float x, float inv) {
    float q = rintf(x * inv);                 // inv = 127/absmax (one div per row)
    q = fminf(fmaxf(q, -QMAX), QMAX);
    return (int)q;                            // exact: q integral, |q|<=127
}

__device__ inline uint32_t pack4(float4 v, float inv) {
    return (uint32_t)(quant_i(v.x, inv) & 255)
         | ((uint32_t)(quant_i(v.y, inv) & 255) << 8)
         | ((uint32_t)(quant_i(v.z, inv) & 255) << 16)
         | ((uint32_t)(quant_i(v.w, inv) & 255) << 24);
}

__device__ inline float amax8(float4 a, float4 b) {
    return fmaxf(fmaxf(fmaxf(fabsf(a.x), fabsf(a.y)), fmaxf(fabsf(a.z), fabsf(a.w))),
                 fmaxf(fmaxf(fabsf(b.x), fabsf(b.y)), fmaxf(fabsf(b.z), fabsf(b.w))));
}

// ---- kernel 1: quantize rhs along axis 0 (per column f), store B^T int8 [F][K] ----
__global__ void quant_rhs_kernel(const float* __restrict__ rhs,
                                 int8_t* __restrict__ Bt,
                                 float* __restrict__ rscale) {
    const int f = blockIdx.x;      // column 0..511
    const int t = threadIdx.x;     // 0..63
    float v[8];
    float amax = 0.f;
#pragma unroll
    for (int i = 0; i < 8; ++i) {
        v[i] = rhs[(size_t)(t + 64 * i) * 512 + f];
        amax = fmaxf(amax, fabsf(v[i]));
    }
#pragma unroll
    for (int m = 1; m <= 32; m <<= 1)
        amax = fmaxf(amax, __shfl_xor(amax, m, 64));
    const float inv = amax > 0.f ? QMAX / amax : 0.f;
    if (t == 0) rscale[f] = amax > 0.f ? amax * (1.0f / QMAX) : 1.0f;
#pragma unroll
    for (int i = 0; i < 8; ++i)
        Bt[(size_t)f * 512 + t + 64 * i] = (int8_t)quant_i(v[i], inv);
}

// ---- kernel 2: quantize lhs rows -> int8 Aq [65536][512] + lscale ----
// High-TLP streaming: 32 waves/CU (VGPR<=64), one wave per row, 2-row batches.
__global__ __launch_bounds__(256, 8) void quant_lhs_kernel(const float* __restrict__ lhs,
                                                           int8_t* __restrict__ Aq,
                                                           float* __restrict__ lscale) {
    const int lane = threadIdx.x & 63;
    const int wave = threadIdx.x >> 6;
    const int row0 = blockIdx.x * 32 + wave * 8;   // this wave's 8 rows
    const float* rp = lhs + (size_t)row0 * 512 + lane * 8;
    int8_t* op = Aq + (size_t)row0 * 512 + lane * 8;
#pragma unroll
    for (int r = 0; r < 8; r += 2) {
        const float4 a0 = *(const float4*)(rp + (size_t)r * 512);
        const float4 b0 = *(const float4*)(rp + (size_t)r * 512 + 4);
        const float4 a1 = *(const float4*)(rp + (size_t)(r + 1) * 512);
        const float4 b1 = *(const float4*)(rp + (size_t)(r + 1) * 512 + 4);
        float m0 = amax8(a0, b0);
        float m1 = amax8(a1, b1);
#pragma unroll
        for (int m = 1; m <= 32; m <<= 1) {        // interleaved dual reduce
            m0 = fmaxf(m0, __shfl_xor(m0, m, 64));
            m1 = fmaxf(m1, __shfl_xor(m1, m, 64));
        }
        const float inv0 = m0 > 0.f ? QMAX / m0 : 0.f;
        const float inv1 = m1 > 0.f ? QMAX / m1 : 0.f;
        if (lane == 0) {
            lscale[row0 + r]     = m0 > 0.f ? m0 * (1.0f / QMAX) : 1.0f;
            lscale[row0 + r + 1] = m1 > 0.f ? m1 * (1.0f / QMAX) : 1.0f;
        }
        i32x2 p0, p1;
        p0.x = (int)pack4(a0, inv0); p0.y = (int)pack4(b0, inv0);
        p1.x = (int)pack4(a1, inv1); p1.y = (int)pack4(b1, inv1);
        *(i32x2*)(op + (size_t)r * 512)       = p0;
        *(i32x2*)(op + (size_t)(r + 1) * 512) = p1;
    }
}

// ---- kernel 3: int8 GEMM, m97 skeleton: 128x128 tile, BK=128, 4 waves 2x2 ----
// XCD-aware swizzle: the 4 n-tiles of each m-slab run on the SAME XCD so the
// A-slab is fetched from HBM once and re-read from that XCD's L2.
// LDS XOR-swizzle via pre-swizzled GLOBAL source (m173; gload_lds dest is linear).
__global__ __launch_bounds__(256, 3) void gemm_kernel(const int8_t* __restrict__ Aq,
                                                      const int8_t* __restrict__ Bt,
                                                      const float* __restrict__ lscale,
                                                      const float* __restrict__ rscale,
                                                      float* __restrict__ out) {
    __shared__ int8_t lds[32768];  // A [128][128] @0, B^T [128][128] @16384 (both swizzled)

    const int tid  = threadIdx.x;
    const int lane = tid & 63;
    const int wave = tid >> 6;
    const int wr   = wave >> 1;
    const int wc   = wave & 1;

    // 2048 blocks = 8 XCDs x 256; slab = xcd*64 + j/4, nc = j%4  (bijective)
    const int g   = blockIdx.x;
    const int xcd = g & 7;
    const int j   = g >> 3;
    const int m0  = (xcd * 64 + (j >> 2)) * 128;
    const int n0  = (j & 3) * 128;

    i32x4 acc[4][4];
#pragma unroll
    for (int i = 0; i < 4; ++i)
#pragma unroll
        for (int jj = 0; jj < 4; ++jj)
            acc[i][jj] = (i32x4){0, 0, 0, 0};

    const int lane15 = lane & 15;
    const int laneHi = lane >> 4;

#pragma unroll
    for (int kt = 0; kt < 512; kt += 128) {
        __syncthreads();   // previous step's frags consumed
#pragma unroll
        for (int c = 0; c < 4; ++c) {
            const int chunk = (c * 4 + wave) * 1024;   // wave-uniform 1KB chunk
            const int d     = chunk + lane * 16;       // linear LDS dest byte
            const int row   = d >> 7;                  // tile row (A) / col (B)
            const int koff  = d & 127;                 // 16-aligned
            const int srck  = koff ^ ((row & 7) << 4); // pre-swizzled source k
            const int8_t* srcA = Aq + (size_t)(m0 + row) * 512 + kt + srck;
            __builtin_amdgcn_global_load_lds((GVoid*)srcA, (LVoid*)(lds + chunk), 16, 0, 0);
            const int8_t* srcB = Bt + (size_t)(n0 + row) * 512 + kt + srck;
            __builtin_amdgcn_global_load_lds((GVoid*)srcB, (LVoid*)(lds + 16384 + chunk), 16, 0, 0);
        }
        __syncthreads();   // staging complete (compiler drains vmcnt at barrier)

        i32x4 af[4][2], bf[4][2];
#pragma unroll
        for (int mi = 0; mi < 4; ++mi) {
            const int row = wr * 64 + mi * 16 + lane15;
            const int sw  = (row & 7) << 4;
#pragma unroll
            for (int kk = 0; kk < 2; ++kk) {
                const int kb = kk * 64 + laneHi * 16;
                af[mi][kk] = *(const i32x4*)(lds + row * 128 + (kb ^ sw));
            }
        }
#pragma unroll
        for (int ni = 0; ni < 4; ++ni) {
            const int col = wc * 64 + ni * 16 + lane15;
            const int sw  = (col & 7) << 4;
#pragma unroll
            for (int kk = 0; kk < 2; ++kk) {
                const int kb = kk * 64 + laneHi * 16;
                bf[ni][kk] = *(const i32x4*)(lds + 16384 + col * 128 + (kb ^ sw));
            }
        }
#pragma unroll
        for (int kk = 0; kk < 2; ++kk)
#pragma unroll
            for (int mi = 0; mi < 4; ++mi)
#pragma unroll
                for (int ni = 0; ni < 4; ++ni)
                    acc[mi][ni] = __builtin_amdgcn_mfma_i32_16x16x64_i8(
                        af[mi][kk], bf[ni][kk], acc[mi][ni], 0, 0, 0);
    }

    // ---- epilogue: C/D layout col=lane&15, row=(lane>>4)*4+reg ----
    float rs[4];
#pragma unroll
    for (int ni = 0; ni < 4; ++ni)
        rs[ni] = rscale[n0 + wc * 64 + ni * 16 + lane15];
    const int rg = laneHi * 4;
#pragma unroll
    for (int mi = 0; mi < 4; ++mi) {
#pragma unroll
        for (int r = 0; r < 4; ++r) {
            const int grow = m0 + wr * 64 + mi * 16 + rg + r;
            const float ls = lscale[grow];
            float* op = out + (size_t)grow * 512 + n0 + wc * 64;
#pragma unroll
            for (int ni = 0; ni < 4; ++ni)
                op[ni * 16 + lane15] = (float)acc[mi][ni][r] * ls * rs[ni];
        }
    }
}

extern "C" void kernel_launch(void* const* d_in, const int* in_sizes, int n_in,
                              void* d_out, int out_size, void* d_ws, size_t ws_size,
                              hipStream_t stream) {
    const float* lhs = (const float*)d_in[0];   // [4,16384,512] f32
    const float* rhs = (const float*)d_in[1];   // [512,512] f32
    float* out = (float*)d_out;                 // [4,16384,512] f32

    // ws: Bt i8 [512][512] (256KB) | rscale f32[512] | lscale f32[65536] | Aq i8 [65536][512] (32MB)
    char* ws = (char*)d_ws;
    int8_t* Bt    = (int8_t*)ws;
    float* rscale = (float*)(ws + 262144);
    float* lscale = (float*)(ws + 266240);
    int8_t* Aq    = (int8_t*)(ws + 1048576);

    const int rows = in_sizes[0] / 512;         // 65536

    quant_rhs_kernel<<<512, 64, 0, stream>>>(rhs, Bt, rscale);
    quant_lhs_kernel<<<rows / 32, 256, 0, stream>>>(lhs, Aq, lscale);
    gemm_kernel<<<(rows / 128) * 4, 256, 0, stream>>>(Aq, Bt, lscale, rscale, out);
}